// Round 5
// baseline (405.111 us; speedup 1.0000x reference)
//
#include <hip/hip_runtime.h>

#define HC 60
#define WCC 80
#define NCELL 4800
#define NP 4864          // padded to 38*128
#define NB 38            // NP/128
#define DCH 256
#define BATCH 2
#define QT 64

typedef _Float16 half8 __attribute__((ext_vector_type(8)));
typedef float f32x4 __attribute__((ext_vector_type(4)));

// ---------------- warp coords: (row,col) of warped cell centers -------------
__global__ __launch_bounds__(256) void warp_kernel(const float* __restrict__ H,
                                                   float* __restrict__ wout) {
  int idx = blockIdx.x * 256 + threadIdx.x;
  if (idx >= BATCH * NP) return;
  int b = idx / NP;
  int q = idx - b * NP;
  float wr = 1e9f, wc = 1e9f;   // padded cells: push far away -> S=0
  if (q < NCELL) {
    int i = q / WCC;
    int j = q - i * WCC;
    float x = (float)(j * 8 + 4);
    float y = (float)(i * 8 + 4);
    const float* h = H + b * 9;
    float w0 = h[0] * x + h[1] * y + h[2];
    float w1 = h[3] * x + h[4] * y + h[5];
    float w2 = h[6] * x + h[7] * y + h[8];
    wr = w1 / w2;
    wc = w0 / w2;
  }
  wout[2 * idx]     = wr;
  wout[2 * idx + 1] = wc;
}

// ------ normalize + transpose (b,d,hc,wc) -> padded (b,NP,d) f16, coalesced --
__global__ __launch_bounds__(256) void normalize_kernel(
    const float* __restrict__ desc, const float* __restrict__ wdesc,
    _Float16* __restrict__ dnp, _Float16* __restrict__ wnp) {
  __shared__ _Float16 vt[DCH][QT + 2];
  __shared__ float pss[4][QT];
  __shared__ float invq[QT];
  const int q0 = blockIdx.x * QT;
  const int which = blockIdx.y;
  const int b = blockIdx.z;
  const float* in = which ? wdesc : desc;
  _Float16* out = which ? wnp : dnp;
  const int tx = threadIdx.x & 63;
  const int ty = threadIdx.x >> 6;
  const int q = q0 + tx;
  float ss = 0.f;
  for (int cc = 0; cc < DCH / 4; ++cc) {
    const int c = cc * 4 + ty;
    float v = (q < NCELL) ? in[((size_t)b * DCH + c) * NCELL + q] : 0.f;
    vt[c][tx] = (_Float16)v;
    ss += v * v;
  }
  pss[ty][tx] = ss;
  __syncthreads();
  if (ty == 0) {
    float tot = pss[0][tx] + pss[1][tx] + pss[2][tx] + pss[3][tx];
    invq[tx] = 1.f / fmaxf(sqrtf(tot), 1e-12f);
  }
  __syncthreads();
  for (int it = 0; it < QT; ++it) {
    out[((size_t)b * NP + q0 + it) * DCH + threadIdx.x] =
        (_Float16)((float)vt[threadIdx.x][it] * invq[it]);
  }
}

// -------- GEMM core: direct-from-L2 register fragments, no LDS, no barriers --
// Inputs are 4.75 MB total -> L2-resident; LDS staging was pure overhead at K=256.
// MODE 0: rows=q (A=dn), accumulate r2[q] = sum_t relu(dot)^2
// MODE 1: rows=t (A=wn), cols=q, scale cols by invr[q], accumulate c2[t]
// MODE 2: rows=q, cols=t, v = u*invr[q]*invc[t], margin loss -> lossp slots
template <int MODE>
__global__ __launch_bounds__(256) void gemm_kernel(
    const _Float16* __restrict__ A, const _Float16* __restrict__ Bm,
    const float* __restrict__ invr, const float* __restrict__ colscale,
    const float* __restrict__ warp, float* __restrict__ sqacc,
    float* __restrict__ lossp) {
  const int tid = threadIdx.x;
  const int wave = tid >> 6;
  const int lane = tid & 63;
  const int batch = blockIdx.z;
  const int row0 = blockIdx.y * 128;
  const int col0 = blockIdx.x * 128;

  const int wq_r = wave >> 1;   // wave's 64-row half
  const int wq_c = wave & 1;    // wave's 64-col half
  const int g = lane >> 4;      // 0..3  (k-subgroup; C row subgroup)
  const int cL = lane & 15;     // fragment row/col within 16

  // per-lane fragment base pointers (16B-aligned contiguous half8 loads)
  const _Float16* ap =
      A + ((size_t)batch * NP + row0 + wq_r * 64 + cL) * DCH + g * 8;
  const _Float16* bp =
      Bm + ((size_t)batch * NP + col0 + wq_c * 64 + cL) * DCH + g * 8;

  f32x4 acc[4][4] = {};

#pragma unroll
  for (int ks = 0; ks < 8; ++ks) {   // K = 256 in 8 slices of 32
    half8 af[4], bf[4];
#pragma unroll
    for (int m = 0; m < 4; ++m)
      af[m] = *reinterpret_cast<const half8*>(ap + (size_t)m * 16 * DCH + ks * 32);
#pragma unroll
    for (int n = 0; n < 4; ++n)
      bf[n] = *reinterpret_cast<const half8*>(bp + (size_t)n * 16 * DCH + ks * 32);
#pragma unroll
    for (int m = 0; m < 4; ++m)
#pragma unroll
      for (int n = 0; n < 4; ++n)
        acc[m][n] =
            __builtin_amdgcn_mfma_f32_16x16x32_f16(af[m], bf[n], acc[m][n], 0, 0, 0);
  }

  if (MODE == 0 || MODE == 1) {
    float cs[4];
    if (MODE == 1) {
#pragma unroll
      for (int n = 0; n < 4; ++n)
        cs[n] = colscale[(size_t)batch * NP + col0 + wq_c * 64 + n * 16 + cL];
    }
    float rs[4][4];
#pragma unroll
    for (int m = 0; m < 4; ++m)
#pragma unroll
      for (int j = 0; j < 4; ++j) rs[m][j] = 0.f;
#pragma unroll
    for (int m = 0; m < 4; ++m)
#pragma unroll
      for (int n = 0; n < 4; ++n)
#pragma unroll
        for (int j = 0; j < 4; ++j) {
          float u = fmaxf(acc[m][n][j], 0.f);
          if (MODE == 1) u *= cs[n];
          rs[m][j] += u * u;
        }
#pragma unroll
    for (int m = 0; m < 4; ++m)
#pragma unroll
      for (int j = 0; j < 4; ++j) {
        float v = rs[m][j];
        v += __shfl_xor(v, 1, 64);
        v += __shfl_xor(v, 2, 64);
        v += __shfl_xor(v, 4, 64);
        v += __shfl_xor(v, 8, 64);
        if (cL == 0)
          atomicAdd(&sqacc[(size_t)batch * NP + row0 + wq_r * 64 + m * 16 + g * 4 + j], v);
      }
  } else {
    float cy[4], cx[4], ic[4];
    int cvalid[4];
#pragma unroll
    for (int n = 0; n < 4; ++n) {
      int ct = col0 + wq_c * 64 + n * 16 + cL;
      cvalid[n] = (ct < NCELL);
      int tk = ct / WCC;
      int tl = ct - tk * WCC;
      cy[n] = (float)(tk * 8 + 4);
      cx[n] = (float)(tl * 8 + 4);
      ic[n] = colscale[(size_t)batch * NP + ct];
    }
    float lsum = 0.f;
#pragma unroll
    for (int m = 0; m < 4; ++m)
#pragma unroll
      for (int j = 0; j < 4; ++j) {
        const int rq = row0 + wq_r * 64 + m * 16 + g * 4 + j;
        if (rq < NCELL) {
          const float ir = invr[(size_t)batch * NP + rq];
          const float wr = warp[((size_t)batch * NP + rq) * 2];
          const float wcol = warp[((size_t)batch * NP + rq) * 2 + 1];
#pragma unroll
          for (int n = 0; n < 4; ++n) {
            if (cvalid[n]) {
              float u = fmaxf(acc[m][n][j], 0.f);
              float v = u * ir * ic[n];
              float dr = cy[n] - wr;
              float dc = cx[n] - wcol;
              float pos = 250.f * fmaxf(1.f - v, 0.f);
              float neg = fmaxf(v - 0.2f, 0.f);
              lsum += (dr * dr + dc * dc <= 56.25f) ? pos : neg;
            }
          }
        }
      }
#pragma unroll
    for (int s = 1; s < 64; s <<= 1) lsum += __shfl_xor(lsum, s, 64);
    if (lane == 0) {
      int slot = (((batch * NB + blockIdx.y) * NB + blockIdx.x) << 2) | wave;
      lossp[slot] = lsum;
    }
  }
}

__global__ void finalize_inv(const float* __restrict__ sq, float* __restrict__ inv,
                             int count) {
  int i = blockIdx.x * 256 + threadIdx.x;
  if (i < count) inv[i] = 1.f / fmaxf(sqrtf(sq[i]), 1e-12f);
}

__global__ __launch_bounds__(1024) void loss_reduce(const float* __restrict__ lossp,
                                                    float* __restrict__ out, int count) {
  double s = 0.0;
  for (int i = threadIdx.x; i < count; i += 1024) s += (double)lossp[i];
#pragma unroll
  for (int k = 1; k < 64; k <<= 1) s += __shfl_xor(s, k, 64);
  __shared__ double sd[16];
  if ((threadIdx.x & 63) == 0) sd[threadIdx.x >> 6] = s;
  __syncthreads();
  if (threadIdx.x == 0) {
    double t = 0.0;
    for (int w = 0; w < 16; ++w) t += sd[w];
    out[0] = (float)(t / ((double)NCELL * (double)NCELL));
  }
}

extern "C" void kernel_launch(void* const* d_in, const int* in_sizes, int n_in,
                              void* d_out, int out_size, void* d_ws, size_t ws_size,
                              hipStream_t stream) {
  const float* desc  = (const float*)d_in[0];
  const float* wdesc = (const float*)d_in[1];
  const float* H     = (const float*)d_in[2];
  char* ws = (char*)d_ws;

  constexpr size_t SZ_HALF = (size_t)BATCH * NP * DCH * sizeof(_Float16);
  constexpr size_t SZ_WARP = (size_t)BATCH * NP * 2 * sizeof(float);
  constexpr size_t SZ_VEC  = (size_t)BATCH * NP * sizeof(float);
  constexpr size_t OFF_DNP  = 0;
  constexpr size_t OFF_WNP  = OFF_DNP + SZ_HALF;
  constexpr size_t OFF_WARP = OFF_WNP + SZ_HALF;
  constexpr size_t OFF_R2   = OFF_WARP + SZ_WARP;
  constexpr size_t OFF_INVR = OFF_R2 + SZ_VEC;
  constexpr size_t OFF_C2   = OFF_INVR + SZ_VEC;
  constexpr size_t OFF_INVC = OFF_C2 + SZ_VEC;
  constexpr size_t OFF_LOSS = OFF_INVC + SZ_VEC;

  _Float16* dnp = (_Float16*)(ws + OFF_DNP);
  _Float16* wnp = (_Float16*)(ws + OFF_WNP);
  float* warp = (float*)(ws + OFF_WARP);
  float* r2   = (float*)(ws + OFF_R2);
  float* invr = (float*)(ws + OFF_INVR);
  float* c2   = (float*)(ws + OFF_C2);
  float* invc = (float*)(ws + OFF_INVC);
  float* lossp = (float*)(ws + OFF_LOSS);

  hipMemsetAsync(r2, 0, 4 * SZ_VEC, stream);   // r2, invr, c2, invc

  warp_kernel<<<dim3((BATCH * NP + 255) / 256), 256, 0, stream>>>(H, warp);
  normalize_kernel<<<dim3(NP / QT, 2, BATCH), 256, 0, stream>>>(desc, wdesc, dnp, wnp);

  dim3 gg(NB, NB, BATCH);
  gemm_kernel<0><<<gg, 256, 0, stream>>>(dnp, wnp, nullptr, nullptr, nullptr, r2, nullptr);
  finalize_inv<<<(BATCH * NP + 255) / 256, 256, 0, stream>>>(r2, invr, BATCH * NP);
  gemm_kernel<1><<<gg, 256, 0, stream>>>(wnp, dnp, nullptr, invr, nullptr, c2, nullptr);
  finalize_inv<<<(BATCH * NP + 255) / 256, 256, 0, stream>>>(c2, invc, BATCH * NP);
  gemm_kernel<2><<<gg, 256, 0, stream>>>(dnp, wnp, invr, invc, warp, nullptr, lossp);
  loss_reduce<<<1, 1024, 0, stream>>>(lossp, (float*)d_out, BATCH * NB * NB * 4);
}

// Round 6
// 241.346 us; speedup vs baseline: 1.6785x; 1.6785x over previous
//
#include <hip/hip_runtime.h>

#define HC 60
#define WCC 80
#define NCELL 4800
#define NP 4864          // padded to 38*128
#define NB 38            // NP/128
#define DCH 256
#define BATCH 2
#define QT 64

typedef _Float16 half8 __attribute__((ext_vector_type(8)));
typedef float f32x4 __attribute__((ext_vector_type(4)));

__device__ __forceinline__ void gload_lds16(const void* gp, void* lp) {
  __builtin_amdgcn_global_load_lds(
      (const __attribute__((address_space(1))) void*)gp,
      (__attribute__((address_space(3))) void*)lp, 16, 0, 0);
}

// ---------------- warp coords: (row,col) of warped cell centers -------------
__global__ __launch_bounds__(256) void warp_kernel(const float* __restrict__ H,
                                                   float* __restrict__ wout) {
  int idx = blockIdx.x * 256 + threadIdx.x;
  if (idx >= BATCH * NP) return;
  int b = idx / NP;
  int q = idx - b * NP;
  float wr = 1e9f, wc = 1e9f;   // padded cells: push far away -> S=0
  if (q < NCELL) {
    int i = q / WCC;
    int j = q - i * WCC;
    float x = (float)(j * 8 + 4);
    float y = (float)(i * 8 + 4);
    const float* h = H + b * 9;
    float w0 = h[0] * x + h[1] * y + h[2];
    float w1 = h[3] * x + h[4] * y + h[5];
    float w2 = h[6] * x + h[7] * y + h[8];
    wr = w1 / w2;
    wc = w0 / w2;
  }
  wout[2 * idx]     = wr;
  wout[2 * idx + 1] = wc;
}

// ------ normalize + transpose (b,d,hc,wc) -> padded (b,NP,d) f16, coalesced --
__global__ __launch_bounds__(256) void normalize_kernel(
    const float* __restrict__ desc, const float* __restrict__ wdesc,
    _Float16* __restrict__ dnp, _Float16* __restrict__ wnp) {
  __shared__ _Float16 vt[DCH][QT + 2];
  __shared__ float pss[4][QT];
  __shared__ float invq[QT];
  const int q0 = blockIdx.x * QT;
  const int which = blockIdx.y;
  const int b = blockIdx.z;
  const float* in = which ? wdesc : desc;
  _Float16* out = which ? wnp : dnp;
  const int tx = threadIdx.x & 63;
  const int ty = threadIdx.x >> 6;
  const int q = q0 + tx;
  float ss = 0.f;
  for (int cc = 0; cc < DCH / 4; ++cc) {
    const int c = cc * 4 + ty;
    float v = (q < NCELL) ? in[((size_t)b * DCH + c) * NCELL + q] : 0.f;
    vt[c][tx] = (_Float16)v;
    ss += v * v;
  }
  pss[ty][tx] = ss;
  __syncthreads();
  if (ty == 0) {
    float tot = pss[0][tx] + pss[1][tx] + pss[2][tx] + pss[3][tx];
    invq[tx] = 1.f / fmaxf(sqrtf(tot), 1e-12f);
  }
  __syncthreads();
  for (int it = 0; it < QT; ++it) {
    out[((size_t)b * NP + q0 + it) * DCH + threadIdx.x] =
        (_Float16)((float)vt[threadIdx.x][it] * invq[it]);
  }
}

// ---------------- GEMM core (single-buffer LDS, repacked U store) -----------
// MODE 0 (+STOREU): rows=q (A=dn), accumulate r2[q], store u=relu(dot) f16
// MODE 1: rows=t (A=wn), cols=q, scale cols by invr[q], accumulate c2[t]
// MODE 2: rows=q, cols=t, v = u*invr[q]*invc[t], margin loss -> lossp slots
union GemmSmem {
  struct { _Float16 As[128][64]; _Float16 Bs[128][64]; } g;   // 32 KiB
  _Float16 rp[128][132];                                      // 33.8 KiB repack
};

template <int MODE, bool STOREU>
__global__ __launch_bounds__(256) void gemm_kernel(
    const _Float16* __restrict__ A, const _Float16* __restrict__ Bm,
    const float* __restrict__ invr, const float* __restrict__ colscale,
    const float* __restrict__ warp, float* __restrict__ sqacc,
    float* __restrict__ lossp, _Float16* __restrict__ uout) {
  __shared__ GemmSmem sm;
  const int tid = threadIdx.x;
  const int wave = tid >> 6;
  const int lane = tid & 63;
  const int batch = blockIdx.z;
  const int row0 = blockIdx.y * 128;
  const int col0 = blockIdx.x * 128;
  const _Float16* Ab = A + ((size_t)batch * NP + row0) * DCH;
  const _Float16* Bb = Bm + ((size_t)batch * NP + col0) * DCH;

  const int wq_r = wave >> 1;
  const int wq_c = wave & 1;
  const int g = lane >> 4;
  const int cL = lane & 15;

  f32x4 acc[4][4] = {};

  const int srow = lane >> 3;
  const int scol = lane & 7;
  const int sc_swz = (scol ^ srow) * 8;   // pre-swizzled global col (halfs)

  for (int ks = 0; ks < 4; ++ks) {        // K = 256 in 4 steps of 64
#pragma unroll
    for (int c = 0; c < 4; ++c) {
      const int chunk = wave * 4 + c;     // 1 KiB chunk = 8 rows x 128B
      const int r = chunk * 8 + srow;
      gload_lds16(Ab + (size_t)r * DCH + ks * 64 + sc_swz,
                  (char*)(&sm.g.As[0][0]) + chunk * 1024);
      gload_lds16(Bb + (size_t)r * DCH + ks * 64 + sc_swz,
                  (char*)(&sm.g.Bs[0][0]) + chunk * 1024);
    }
    __syncthreads();   // drains vmcnt for global_load_lds
#pragma unroll
    for (int kk = 0; kk < 2; ++kk) {
      half8 af[4], bf[4];
#pragma unroll
      for (int m = 0; m < 4; ++m) {
        const int row = wq_r * 64 + m * 16 + cL;
        const int c16 = (kk * 4 + g) ^ (row & 7);
        af[m] = *reinterpret_cast<const half8*>(
            (const char*)(&sm.g.As[0][0]) + row * 128 + c16 * 16);
      }
#pragma unroll
      for (int n = 0; n < 4; ++n) {
        const int row = wq_c * 64 + n * 16 + cL;
        const int c16 = (kk * 4 + g) ^ (row & 7);
        bf[n] = *reinterpret_cast<const half8*>(
            (const char*)(&sm.g.Bs[0][0]) + row * 128 + c16 * 16);
      }
#pragma unroll
      for (int m = 0; m < 4; ++m)
#pragma unroll
        for (int n = 0; n < 4; ++n)
          acc[m][n] =
              __builtin_amdgcn_mfma_f32_16x16x32_f16(af[m], bf[n], acc[m][n], 0, 0, 0);
    }
    __syncthreads();
  }

  if (MODE == 0 || MODE == 1) {
    float cs[4];
    if (MODE == 1) {
#pragma unroll
      for (int n = 0; n < 4; ++n)
        cs[n] = colscale[(size_t)batch * NP + col0 + wq_c * 64 + n * 16 + cL];
    }
    float rs[4][4];
#pragma unroll
    for (int m = 0; m < 4; ++m)
#pragma unroll
      for (int j = 0; j < 4; ++j) rs[m][j] = 0.f;
#pragma unroll
    for (int m = 0; m < 4; ++m)
#pragma unroll
      for (int n = 0; n < 4; ++n)
#pragma unroll
        for (int j = 0; j < 4; ++j) {
          float u = fmaxf(acc[m][n][j], 0.f);
          if (MODE == 1) u *= cs[n];
          rs[m][j] += u * u;
        }
#pragma unroll
    for (int m = 0; m < 4; ++m)
#pragma unroll
      for (int j = 0; j < 4; ++j) {
        float v = rs[m][j];
        v += __shfl_xor(v, 1, 64);
        v += __shfl_xor(v, 2, 64);
        v += __shfl_xor(v, 4, 64);
        v += __shfl_xor(v, 8, 64);
        if (cL == 0)
          atomicAdd(&sqacc[(size_t)batch * NP + row0 + wq_r * 64 + m * 16 + g * 4 + j], v);
      }
    if (STOREU) {
      // repack acc -> padded LDS tile, then fully-coalesced half8 stores
#pragma unroll
      for (int m = 0; m < 4; ++m)
#pragma unroll
        for (int n = 0; n < 4; ++n)
#pragma unroll
          for (int j = 0; j < 4; ++j)
            sm.rp[wq_r * 64 + m * 16 + g * 4 + j][wq_c * 64 + n * 16 + cL] =
                (_Float16)fmaxf(acc[m][n][j], 0.f);
      __syncthreads();
      const int rl = tid >> 4;   // 0..15
      const int uu = tid & 15;   // 0..15
#pragma unroll
      for (int p = 0; p < 8; ++p) {
        const int row = p * 16 + rl;
        half8 hv = *reinterpret_cast<const half8*>(&sm.rp[row][uu * 8]);
        *reinterpret_cast<half8*>(
            &uout[((size_t)batch * NP + row0 + row) * NP + col0 + uu * 8]) = hv;
      }
    }
  } else if (MODE == 2) {
    float cy[4], cx[4], ic[4];
    int cvalid[4];
#pragma unroll
    for (int n = 0; n < 4; ++n) {
      int ct = col0 + wq_c * 64 + n * 16 + cL;
      cvalid[n] = (ct < NCELL);
      int tk = ct / WCC;
      int tl = ct - tk * WCC;
      cy[n] = (float)(tk * 8 + 4);
      cx[n] = (float)(tl * 8 + 4);
      ic[n] = colscale[(size_t)batch * NP + ct];
    }
    float lsum = 0.f;
#pragma unroll
    for (int m = 0; m < 4; ++m)
#pragma unroll
      for (int j = 0; j < 4; ++j) {
        const int rq = row0 + wq_r * 64 + m * 16 + g * 4 + j;
        if (rq < NCELL) {
          const float ir = invr[(size_t)batch * NP + rq];
          const float wr = warp[((size_t)batch * NP + rq) * 2];
          const float wcol = warp[((size_t)batch * NP + rq) * 2 + 1];
#pragma unroll
          for (int n = 0; n < 4; ++n) {
            if (cvalid[n]) {
              float u = fmaxf(acc[m][n][j], 0.f);
              float v = u * ir * ic[n];
              float dr = cy[n] - wr;
              float dc = cx[n] - wcol;
              float pos = 250.f * fmaxf(1.f - v, 0.f);
              float neg = fmaxf(v - 0.2f, 0.f);
              lsum += (dr * dr + dc * dc <= 56.25f) ? pos : neg;
            }
          }
        }
      }
#pragma unroll
    for (int s = 1; s < 64; s <<= 1) lsum += __shfl_xor(lsum, s, 64);
    if (lane == 0) {
      int slot = (((batch * NB + blockIdx.y) * NB + blockIdx.x) << 2) | wave;
      lossp[slot] = lsum;
    }
  }
}

// ---- pass B: c2[t] += sum_q (u[q][t]/r_q)^2 — 1520 blocks, 4-deep loads ----
__global__ __launch_bounds__(256) void passB_kernel(const _Float16* __restrict__ u,
                                                    const float* __restrict__ r2,
                                                    float* __restrict__ c2) {
  const int b = blockIdx.z;
  const int lt = threadIdx.x & 63;        // t-lane (x8 halfs = 512 t per block)
  const int lq = threadIdx.x >> 6;        // 0..3 q-subgroup
  const int t0 = blockIdx.x * 512 + lt * 8;
  const int q0 = blockIdx.y * 64 + lq * 16;
  float s[8];
#pragma unroll
  for (int i = 0; i < 8; ++i) s[i] = 0.f;
  if (t0 < NP) {
    const _Float16* up = u + ((size_t)b * NP + q0) * NP + t0;
    const float* r2p = r2 + b * NP + q0;
#pragma unroll 4
    for (int q = 0; q < 16; ++q) {
      const float ir = 1.f / fmaxf(sqrtf(r2p[q]), 1e-12f);
      half8 h = *reinterpret_cast<const half8*>(up + (size_t)q * NP);
#pragma unroll
      for (int i = 0; i < 8; ++i) {
        float v = (float)h[i] * ir;
        s[i] += v * v;
      }
    }
  }
  __shared__ float red[4][64][9];   // pad 9 -> conflict-free
#pragma unroll
  for (int i = 0; i < 8; ++i) red[lq][lt][i] = s[i];
  __syncthreads();
  if (lq == 0 && t0 < NP) {
#pragma unroll
    for (int i = 0; i < 8; ++i) {
      float tot = red[0][lt][i] + red[1][lt][i] + red[2][lt][i] + red[3][lt][i];
      atomicAdd(&c2[b * NP + t0 + i], tot);
    }
  }
}

// ---- pass C: margin loss — 760 blocks, 4-deep loads ------------------------
__global__ __launch_bounds__(256) void passC_kernel(const _Float16* __restrict__ u,
                                                    const float* __restrict__ r2,
                                                    const float* __restrict__ c2,
                                                    const float* __restrict__ warp,
                                                    float* __restrict__ lossp) {
  const int b = blockIdx.z;
  const int lt = threadIdx.x & 63;
  const int lq = threadIdx.x >> 6;        // wave id
  const int t0 = blockIdx.x * 512 + lt * 8;
  const int q0 = blockIdx.y * 128 + lq * 32;
  float cy[8], cx[8], ic[8];
  bool val[8];
  const bool act = (t0 < NP);
#pragma unroll
  for (int i = 0; i < 8; ++i) {
    const int t = act ? (t0 + i) : 0;
    val[i] = act && (t < NCELL);
    const int tk = t / WCC;
    const int tl = t - tk * WCC;
    cy[i] = (float)(tk * 8 + 4);
    cx[i] = (float)(tl * 8 + 4);
    ic[i] = val[i] ? 1.f / fmaxf(sqrtf(c2[b * NP + t]), 1e-12f) : 0.f;
  }
  float lsum = 0.f;
  if (act) {
    const _Float16* up = u + ((size_t)b * NP + q0) * NP + t0;
#pragma unroll 4
    for (int q = 0; q < 32; ++q) {
      const int qq = q0 + q;
      const float ir = 1.f / fmaxf(sqrtf(r2[b * NP + qq]), 1e-12f);
      const float wr = warp[(size_t)(b * NP + qq) * 2];
      const float wc = warp[(size_t)(b * NP + qq) * 2 + 1];
      half8 h = *reinterpret_cast<const half8*>(up + (size_t)q * NP);
#pragma unroll
      for (int i = 0; i < 8; ++i) {
        if (val[i]) {
          float v = (float)h[i] * ir * ic[i];
          float dr = cy[i] - wr;
          float dc = cx[i] - wc;
          float pos = 250.f * fmaxf(1.f - v, 0.f);
          float neg = fmaxf(v - 0.2f, 0.f);
          lsum += (dr * dr + dc * dc <= 56.25f) ? pos : neg;
        }
      }
    }
  }
#pragma unroll
  for (int s = 1; s < 64; s <<= 1) lsum += __shfl_xor(lsum, s, 64);
  if (lt == 0)
    lossp[(((b * NB + blockIdx.y) * 10 + blockIdx.x) << 2) | lq] = lsum;
}

__global__ void finalize_inv(const float* __restrict__ sq, float* __restrict__ inv,
                             int count) {
  int i = blockIdx.x * 256 + threadIdx.x;
  if (i < count) inv[i] = 1.f / fmaxf(sqrtf(sq[i]), 1e-12f);
}

__global__ __launch_bounds__(1024) void loss_reduce(const float* __restrict__ lossp,
                                                    float* __restrict__ out, int count) {
  double s = 0.0;
  for (int i = threadIdx.x; i < count; i += 1024) s += (double)lossp[i];
#pragma unroll
  for (int k = 1; k < 64; k <<= 1) s += __shfl_xor(s, k, 64);
  __shared__ double sd[16];
  if ((threadIdx.x & 63) == 0) sd[threadIdx.x >> 6] = s;
  __syncthreads();
  if (threadIdx.x == 0) {
    double t = 0.0;
    for (int w = 0; w < 16; ++w) t += sd[w];
    out[0] = (float)(t / ((double)NCELL * (double)NCELL));
  }
}

extern "C" void kernel_launch(void* const* d_in, const int* in_sizes, int n_in,
                              void* d_out, int out_size, void* d_ws, size_t ws_size,
                              hipStream_t stream) {
  const float* desc  = (const float*)d_in[0];
  const float* wdesc = (const float*)d_in[1];
  const float* H     = (const float*)d_in[2];
  char* ws = (char*)d_ws;

  constexpr size_t SZ_HALF = (size_t)BATCH * NP * DCH * sizeof(_Float16);
  constexpr size_t SZ_WARP = (size_t)BATCH * NP * 2 * sizeof(float);
  constexpr size_t SZ_VEC  = (size_t)BATCH * NP * sizeof(float);
  constexpr size_t SZ_LOSS = (size_t)BATCH * NB * 10 * 4 * sizeof(float);  // >= both paths
  constexpr size_t SZ_U    = (size_t)BATCH * NP * NP * sizeof(_Float16);   // ~94.6 MB
  constexpr size_t OFF_DNP  = 0;
  constexpr size_t OFF_WNP  = OFF_DNP + SZ_HALF;
  constexpr size_t OFF_WARP = OFF_WNP + SZ_HALF;
  constexpr size_t OFF_R2   = OFF_WARP + SZ_WARP;
  constexpr size_t OFF_C2   = OFF_R2 + SZ_VEC;
  constexpr size_t OFF_INVR = OFF_C2 + SZ_VEC;
  constexpr size_t OFF_INVC = OFF_INVR + SZ_VEC;
  constexpr size_t OFF_LOSS = OFF_INVC + SZ_VEC;
  constexpr size_t SZ_LOSS2 = (size_t)BATCH * NB * NB * 4 * sizeof(float);
  constexpr size_t OFF_U    = OFF_LOSS + (SZ_LOSS > SZ_LOSS2 ? SZ_LOSS : SZ_LOSS2);
  constexpr size_t TOTAL    = OFF_U + SZ_U;

  _Float16* dnp = (_Float16*)(ws + OFF_DNP);
  _Float16* wnp = (_Float16*)(ws + OFF_WNP);
  float* warp = (float*)(ws + OFF_WARP);
  float* r2   = (float*)(ws + OFF_R2);
  float* c2   = (float*)(ws + OFF_C2);
  float* invr = (float*)(ws + OFF_INVR);
  float* invc = (float*)(ws + OFF_INVC);
  float* lossp = (float*)(ws + OFF_LOSS);
  _Float16* u = (_Float16*)(ws + OFF_U);

  hipMemsetAsync(r2, 0, 2 * SZ_VEC, stream);   // r2, c2

  warp_kernel<<<dim3((BATCH * NP + 255) / 256), 256, 0, stream>>>(H, warp);
  normalize_kernel<<<dim3(NP / QT, 2, BATCH), 256, 0, stream>>>(desc, wdesc, dnp, wnp);

  dim3 gg(NB, NB, BATCH);
  if (ws_size >= TOTAL) {
    gemm_kernel<0, true><<<gg, 256, 0, stream>>>(dnp, wnp, nullptr, nullptr, nullptr,
                                                 r2, nullptr, u);
    passB_kernel<<<dim3(10, 76, BATCH), 256, 0, stream>>>(u, r2, c2);
    passC_kernel<<<dim3(10, NB, BATCH), 256, 0, stream>>>(u, r2, c2, warp, lossp);
    loss_reduce<<<1, 1024, 0, stream>>>(lossp, (float*)d_out, BATCH * NB * 10 * 4);
  } else {
    gemm_kernel<0, false><<<gg, 256, 0, stream>>>(dnp, wnp, nullptr, nullptr, nullptr,
                                                  r2, nullptr, nullptr);
    finalize_inv<<<(BATCH * NP + 255) / 256, 256, 0, stream>>>(r2, invr, BATCH * NP);
    gemm_kernel<1, false><<<gg, 256, 0, stream>>>(wnp, dnp, nullptr, invr, nullptr,
                                                  c2, nullptr, nullptr);
    finalize_inv<<<(BATCH * NP + 255) / 256, 256, 0, stream>>>(c2, invc, BATCH * NP);
    gemm_kernel<2, false><<<gg, 256, 0, stream>>>(dnp, wnp, invr, invc, warp,
                                                  nullptr, lossp, nullptr);
    loss_reduce<<<1, 1024, 0, stream>>>(lossp, (float*)d_out, BATCH * NB * NB * 4);
  }
}